// Round 4
// baseline (16954.213 us; speedup 1.0000x reference)
//
#include <hip/hip_runtime.h>
#include <math.h>

#define N_PTS 16384
#define KNN 20
#define NRANGE 8
#define C_RANGE (N_PTS / NRANGE)      // 2048
#define TILES_PER_RANGE (C_RANGE / 64) // 32

// ---------------- pack x + squared norm ----------------
__global__ void pack3_kernel(const float* __restrict__ x, float4* __restrict__ xp) {
  int i = blockIdx.x * blockDim.x + threadIdx.x;
  {
    #pragma clang fp contract(off)
    float a = x[i*3+0], b = x[i*3+1], c = x[i*3+2];
    xp[i] = make_float4(a, b, c, a*a + b*b + c*c);
  }
}

__global__ void sq64_kernel(const float* __restrict__ h, float* __restrict__ sq) {
  int i = blockIdx.x * blockDim.x + threadIdx.x;
  const float4* r = (const float4*)(h + (long)i*64);
  {
    #pragma clang fp contract(off)
    float ax=0.f, ay=0.f, az=0.f, aw=0.f;
    for (int t=0; t<16; t++) {
      float4 v = r[t];
      ax += v.x*v.x; ay += v.y*v.y; az += v.z*v.z; aw += v.w*v.w;
    }
    sq[i] = (ax+ay)+(az+aw);
  }
}

// lex insert of survivor (d, idx) into sorted top-20 (ld stride 21)
__device__ __forceinline__ void lex_insert(float* ldq, int* liq, float d, int idx) {
  float d19 = ldq[KNN-1]; int i19 = liq[KNN-1];
  if (d < d19 || (d == d19 && idx < i19)) {
    int p = KNN-1;
    while (p > 0) {
      float pd = ldq[p-1]; int pi = liq[p-1];
      if (pd > d || (pd == d && pi > idx)) { ldq[p] = pd; liq[p] = pi; p--; }
      else break;
    }
    ldq[p] = d; liq[p] = idx;
  }
}

// ---------------- knn D=64, tiled + filtered selection ----------------
__global__ __launch_bounds__(256, 2) void knn64_tiled(const float* __restrict__ h,
                                                      const float* __restrict__ sq,
                                                      float* __restrict__ pd,
                                                      int* __restrict__ pi) {
  __shared__ float qbuf[64][68];   // [r][64] = sq(query)
  __shared__ float cbuf[64][68];   // [r][64] = sq(candidate)
  __shared__ float ld[64][21];
  __shared__ int   li[64][21];
  __shared__ float candd[64*65];
  __shared__ int   candi[64*65];
  __shared__ int   cnt[64];
  __shared__ float w19[64];
  int tid = threadIdx.x;
  int qb = blockIdx.x >> 3;
  int rg = blockIdx.x & 7;
  int q0 = qb*64, c0 = rg*C_RANGE;

  for (int t = tid; t < 64*16; t += 256) {
    int r = t >> 4, cc = t & 15;
    *(float4*)&qbuf[r][cc*4] = *(const float4*)(h + (size_t)(q0+r)*64 + cc*4);
  }
  if (tid < 64) { qbuf[tid][64] = sq[q0+tid]; cnt[tid] = 0; w19[tid] = INFINITY; }
  for (int t = tid; t < 64*KNN; t += 256) { ld[t/KNN][t%KNN] = INFINITY; li[t/KNN][t%KNN] = 0x7fffffff; }

  int qrow0 = (tid >> 4) * 4;   // 16 groups of 4 query rows
  int tx = tid & 15;
  int crow0 = tx * 4;           // 16 groups of 4 candidate rows

  for (int tile = 0; tile < TILES_PER_RANGE; tile++) {
    int ct0 = c0 + tile*64;
    for (int t = tid; t < 64*16; t += 256) {
      int r = t >> 4, cc = t & 15;
      *(float4*)&cbuf[r][cc*4] = *(const float4*)(h + (size_t)(ct0+r)*64 + cc*4);
    }
    if (tid < 64) cbuf[tid][64] = sq[ct0+tid];
    __syncthreads();

    float acc[4][4];
    #pragma unroll
    for (int i=0;i<4;i++)
      #pragma unroll
      for (int j=0;j<4;j++) acc[i][j] = 0.f;

    #pragma unroll
    for (int dc = 0; dc < 16; dc++) {
      float4 qv[4], cv[4];
      #pragma unroll
      for (int i=0;i<4;i++) qv[i] = *(float4*)&qbuf[qrow0+i][dc*4];
      #pragma unroll
      for (int j=0;j<4;j++) cv[j] = *(float4*)&cbuf[crow0+j][dc*4];
      #pragma unroll
      for (int i=0;i<4;i++)
        #pragma unroll
        for (int j=0;j<4;j++)
          acc[i][j] += qv[i].x*cv[j].x + qv[i].y*cv[j].y + qv[i].z*cv[j].z + qv[i].w*cv[j].w;
    }

    float qs[4], cs[4];
    #pragma unroll
    for (int i=0;i<4;i++) qs[i] = qbuf[qrow0+i][64];
    #pragma unroll
    for (int j=0;j<4;j++) cs[j] = cbuf[crow0+j][64];

    // filter + push survivors (distance identical to round-3 formula)
    #pragma unroll
    for (int i=0;i<4;i++) {
      int q = qrow0 + i;
      float w = w19[q];
      #pragma unroll
      for (int j=0;j<4;j++) {
        float d = (qs[i] + cs[j]) - 2.0f*acc[i][j];
        if (d < w) {
          int slot = atomicAdd(&cnt[q], 1);
          candd[q*65 + slot] = d;
          candi[q*65 + slot] = ct0 + crow0 + j;
        }
      }
    }
    __syncthreads();

    if (tid < 64) {
      int n = cnt[tid];
      for (int s = 0; s < n; s++)
        lex_insert(ld[tid], li[tid], candd[tid*65+s], candi[tid*65+s]);
      w19[tid] = ld[tid][KNN-1];
      cnt[tid] = 0;
    }
    // next iteration's post-staging __syncthreads orders phase2 vs phase1
  }

  __syncthreads();
  for (int t = tid; t < 64*KNN; t += 256) {
    int q = t / KNN, k = t % KNN;
    size_t o = ((size_t)(q0+q)*NRANGE + rg)*KNN + k;
    pd[o] = ld[q][k];
    pi[o] = li[q][k];
  }
}

// ---------------- knn D=3 (packed float4), tiled + filtered selection ----------------
__global__ __launch_bounds__(256) void knn3_tiled(const float4* __restrict__ xp,
                                                  float* __restrict__ pd,
                                                  int* __restrict__ pi) {
  __shared__ float4 qb4[64];
  __shared__ float4 cb4[64];
  __shared__ float ld[64][21];
  __shared__ int   li[64][21];
  __shared__ float candd[64*65];
  __shared__ int   candi[64*65];
  __shared__ int   cnt[64];
  __shared__ float w19[64];
  int tid = threadIdx.x;
  int qb = blockIdx.x >> 3;
  int rg = blockIdx.x & 7;
  int q0 = qb*64, c0 = rg*C_RANGE;

  if (tid < 64) { qb4[tid] = xp[q0+tid]; cnt[tid] = 0; w19[tid] = INFINITY; }
  for (int t = tid; t < 64*KNN; t += 256) { ld[t/KNN][t%KNN] = INFINITY; li[t/KNN][t%KNN] = 0x7fffffff; }

  int qrow0 = (tid >> 4) * 4;
  int tx = tid & 15;
  int crow0 = tx * 4;

  for (int tile = 0; tile < TILES_PER_RANGE; tile++) {
    int ct0 = c0 + tile*64;
    if (tid < 64) cb4[tid] = xp[ct0+tid];
    __syncthreads();

    float4 qv[4], cv[4];
    #pragma unroll
    for (int i=0;i<4;i++) qv[i] = qb4[qrow0+i];
    #pragma unroll
    for (int j=0;j<4;j++) cv[j] = cb4[crow0+j];
    #pragma unroll
    for (int i=0;i<4;i++) {
      int q = qrow0 + i;
      float w = w19[q];
      #pragma unroll
      for (int j=0;j<4;j++) {
        float d = (qv[i].w + cv[j].w)
                - 2.0f*(qv[i].x*cv[j].x + qv[i].y*cv[j].y + qv[i].z*cv[j].z);
        if (d < w) {
          int slot = atomicAdd(&cnt[q], 1);
          candd[q*65 + slot] = d;
          candi[q*65 + slot] = ct0 + crow0 + j;
        }
      }
    }
    __syncthreads();

    if (tid < 64) {
      int n = cnt[tid];
      for (int s = 0; s < n; s++)
        lex_insert(ld[tid], li[tid], candd[tid*65+s], candi[tid*65+s]);
      w19[tid] = ld[tid][KNN-1];
      cnt[tid] = 0;
    }
  }

  __syncthreads();
  for (int t = tid; t < 64*KNN; t += 256) {
    int q = t / KNN, k = t % KNN;
    size_t o = ((size_t)(q0+q)*NRANGE + rg)*KNN + k;
    pd[o] = ld[q][k];
    pi[o] = li[q][k];
  }
}

// ---------------- merge 8 sorted partial lists -> top-20 ----------------
__global__ void knn_merge_kernel(const float* __restrict__ pd, const int* __restrict__ pi,
                                 int* __restrict__ out_idx) {
  int qi = blockIdx.x*256 + threadIdx.x;
  const float* bd = pd + (size_t)qi*NRANGE*KNN;
  const int*   bi = pi + (size_t)qi*NRANGE*KNN;
  int ptr[NRANGE];
  #pragma unroll
  for (int r=0;r<NRANGE;r++) ptr[r] = 0;
  for (int k = 0; k < KNN; k++) {
    float best = INFINITY; int besti = 0x7fffffff; int br = 0;
    #pragma unroll
    for (int r = 0; r < NRANGE; r++) {
      float d = bd[r*KNN + ptr[r]];
      int   ii = bi[r*KNN + ptr[r]];
      bool better = (ptr[r] < KNN) && (d < best || (d == best && ii < besti));
      if (better) { best = d; besti = ii; br = r; }
    }
    #pragma unroll
    for (int r=0;r<NRANGE;r++) ptr[r] += (r == br) ? 1 : 0;
    out_idx[qi*KNN + k] = besti;
  }
}

// ---------------- edge_conv1 precompute ----------------
__global__ void cg1_kernel(const float* __restrict__ x, const float* __restrict__ W1,
                           const float* __restrict__ b1,
                           float* __restrict__ C1, float* __restrict__ G1) {
  int gid = blockIdx.x*256 + threadIdx.x;   // 16384*64
  int i = gid >> 6, c = gid & 63;
  float x0 = x[i*3+0], x1 = x[i*3+1], x2 = x[i*3+2];
  float wt0 = W1[0*64+c], wt1 = W1[1*64+c], wt2 = W1[2*64+c];
  float wb0 = W1[3*64+c], wb1 = W1[4*64+c], wb2 = W1[5*64+c];
  C1[gid] = x0*(wt0-wb0) + x1*(wt1-wb1) + x2*(wt2-wb2) + b1[c];
  G1[gid] = x0*wb0 + x1*wb1 + x2*wb2;
}

// ---------------- gather + max + relu ----------------
template<int C>
__global__ void maxrelu_kernel(const float* __restrict__ Ci, const float* __restrict__ G,
                               const int* __restrict__ idx, float* __restrict__ out) {
  int gid = blockIdx.x*256 + threadIdx.x;
  int i = gid / C, c = gid % C;
  float base = Ci[gid];
  float m = -INFINITY;
  for (int j=0; j<KNN; j++) {
    int jj = idx[i*KNN + j];
    m = fmaxf(m, base + G[(long)jj*C + c]);
  }
  out[gid] = fmaxf(m, 0.0f);
}

// ---------------- W2 diff ----------------
__global__ void wd2_kernel(const float* __restrict__ W2, float* __restrict__ Wd) {
  int gid = blockIdx.x*256 + threadIdx.x;   // 64*128
  int d = gid >> 7, c = gid & 127;
  Wd[gid] = W2[d*128+c] - W2[(d+64)*128+c];
}

// ---------------- edge_conv2 precompute ----------------
__global__ void cg2_kernel(const float* __restrict__ h1, const float* __restrict__ W2,
                           const float* __restrict__ Wd, const float* __restrict__ b2,
                           float* __restrict__ C2, float* __restrict__ G2) {
  int gid = blockIdx.x*256 + threadIdx.x;   // 16384*128
  int i = gid >> 7, c = gid & 127;
  float a = 0.f, g = 0.f;
  for (int d=0; d<64; d++) {
    float hv = h1[i*64 + d];
    a += hv * Wd[d*128 + c];
    g += hv * W2[(d+64)*128 + c];
  }
  C2[gid] = a + b2[c];
  G2[gid] = g;
}

// ---------------- fc1 (relu) ----------------
__global__ void fc1_kernel(const float* __restrict__ h2, const float* __restrict__ w,
                           const float* __restrict__ b, float* __restrict__ out) {
  int gid = blockIdx.x*256 + threadIdx.x;   // 16384*128
  int i = gid >> 7, c = gid & 127;
  float a = 0.f;
  for (int d=0; d<128; d++) a += h2[i*128+d] * w[d*128+c];
  out[gid] = fmaxf(a + b[c], 0.0f);
}

// ---------------- fc2 ----------------
__global__ void fc2_kernel(const float* __restrict__ f1, const float* __restrict__ w,
                           const float* __restrict__ b, float* __restrict__ out) {
  int gid = blockIdx.x*256 + threadIdx.x;   // 16384*40
  int i = gid / 40, c = gid - i*40;
  float a = 0.f;
  for (int d=0; d<128; d++) a += f1[i*128+d] * w[d*40+c];
  out[gid] = a + b[c];
}

extern "C" void kernel_launch(void* const* d_in, const int* in_sizes, int n_in,
                              void* d_out, int out_size, void* d_ws, size_t ws_size,
                              hipStream_t stream) {
  (void)in_sizes; (void)n_in; (void)out_size; (void)ws_size;
  const float* x     = (const float*)d_in[0];
  const float* W1    = (const float*)d_in[1];
  const float* b1    = (const float*)d_in[2];
  const float* W2    = (const float*)d_in[3];
  const float* b2    = (const float*)d_in[4];
  const float* fc1_w = (const float*)d_in[5];
  const float* fc1_b = (const float*)d_in[6];
  const float* fc2_w = (const float*)d_in[7];
  const float* fc2_b = (const float*)d_in[8];
  float* out = (float*)d_out;

  // ---- workspace layout (31.03 MB total, aliased) ----
  char* ws = (char*)d_ws;
  float4* xp4 = (float4*)(ws + 0);          // 262144
  float*  sqh = (float*) (ws + 262144);     // 65536
  int*    idx = (int*)   (ws + 327680);     // 1310720
  float*  Wd2 = (float*) (ws + 1638400);    // 32768
  float*  h1  = (float*) (ws + 1671168);    // 4194304  -> ends 5865472
  float*  h2  = (float*) (ws + 5865472);    // 8388608  -> ends 14254080
  float*  A   = (float*) (ws + 14254080);   // 8388608  -> ends 22642688
  float*  C1  = A;
  float*  G1  = (float*) (ws + 14254080 + 4194304);
  float*  C2  = A;
  float*  f1  = A;
  float*  G2  = (float*) (ws + 22642688);   // 8388608  -> ends 31031296
  float*  pd  = (float*) (ws + 5865472);    // 10485760 -> ends 16351232 (aliases h2 area, dead then)
  int*    pi  = (int*)   (ws + 16351232);   // 10485760 -> ends 26836992

  pack3_kernel <<<64,   256, 0, stream>>>(x, xp4);
  knn3_tiled   <<<2048, 256, 0, stream>>>(xp4, pd, pi);
  knn_merge_kernel<<<64,256, 0, stream>>>(pd, pi, idx);
  cg1_kernel   <<<4096, 256, 0, stream>>>(x, W1, b1, C1, G1);
  maxrelu_kernel<64> <<<4096, 256, 0, stream>>>(C1, G1, idx, h1);
  sq64_kernel  <<<64,   256, 0, stream>>>(h1, sqh);
  knn64_tiled  <<<2048, 256, 0, stream>>>(h1, sqh, pd, pi);
  knn_merge_kernel<<<64,256, 0, stream>>>(pd, pi, idx);
  wd2_kernel   <<<32,   256, 0, stream>>>(W2, Wd2);
  cg2_kernel   <<<8192, 256, 0, stream>>>(h1, W2, Wd2, b2, C2, G2);
  maxrelu_kernel<128><<<8192, 256, 0, stream>>>(C2, G2, idx, h2);
  fc1_kernel   <<<8192, 256, 0, stream>>>(h2, fc1_w, fc1_b, f1);
  fc2_kernel   <<<2560, 256, 0, stream>>>(f1, fc2_w, fc2_b, out);
}

// Round 5
// 5257.335 us; speedup vs baseline: 3.2249x; 3.2249x over previous
//
#include <hip/hip_runtime.h>
#include <math.h>

#define N_PTS 16384
#define KNN 20
#define NRANGE 4
#define C_RANGE (N_PTS / NRANGE)       // 4096
#define TILES_PER_RANGE (C_RANGE / 64) // 64

// ---------------- pack x + squared norm ----------------
__global__ void pack3_kernel(const float* __restrict__ x, float4* __restrict__ xp) {
  int i = blockIdx.x * blockDim.x + threadIdx.x;
  {
    #pragma clang fp contract(off)
    float a = x[i*3+0], b = x[i*3+1], c = x[i*3+2];
    xp[i] = make_float4(a, b, c, a*a + b*b + c*c);
  }
}

__global__ void sq64_kernel(const float* __restrict__ h, float* __restrict__ sq) {
  int i = blockIdx.x * blockDim.x + threadIdx.x;
  const float4* r = (const float4*)(h + (long)i*64);
  {
    #pragma clang fp contract(off)
    float ax=0.f, ay=0.f, az=0.f, aw=0.f;
    for (int t=0; t<16; t++) {
      float4 v = r[t];
      ax += v.x*v.x; ay += v.y*v.y; az += v.z*v.z; aw += v.w*v.w;
    }
    sq[i] = (ax+ay)+(az+aw);
  }
}

// lex insert of survivor (d, idx) into sorted top-20 (row stride 21)
__device__ __forceinline__ void lex_insert(float* ldq, int* liq, float d, int idx) {
  float d19 = ldq[KNN-1]; int i19 = liq[KNN-1];
  if (d < d19 || (d == d19 && idx < i19)) {
    int p = KNN-1;
    while (p > 0) {
      float pd = ldq[p-1]; int pi = liq[p-1];
      if (pd > d || (pd == d && pi > idx)) { ldq[p] = pd; liq[p] = pi; p--; }
      else break;
    }
    ldq[p] = d; liq[p] = idx;
  }
}

// ---------------- knn D=64: transposed tiles, filtered selection ----------------
__global__ __launch_bounds__(256, 2) void knn64_tiled(const float* __restrict__ h,
                                                      const float* __restrict__ sq,
                                                      float* __restrict__ pd,
                                                      int* __restrict__ pi) {
  __shared__ float qT[64][65];    // [dim][query]
  __shared__ float cT[64][65];    // [dim][cand]
  __shared__ float qs[64], cs[64];
  __shared__ float ld[64][21];
  __shared__ int   li[64][21];
  __shared__ float candd[64*65];
  __shared__ int   candi[64*65];
  __shared__ int   cnt[64];
  __shared__ float w19[64];
  int tid = threadIdx.x;
  int qb = blockIdx.x >> 2;
  int rg = blockIdx.x & 3;
  int q0 = qb*64, c0 = rg*C_RANGE;

  // stage qT (transposed): coalesced global, <=4-way LDS scalar writes
  {
    int m = tid & 15;            // float4 chunk within row
    int rbase = tid >> 4;        // 0..15
    #pragma unroll
    for (int p = 0; p < 4; p++) {
      int r = rbase + p*16;
      float4 v = *(const float4*)(h + (size_t)(q0+r)*64 + m*4);
      qT[m*4+0][r] = v.x; qT[m*4+1][r] = v.y; qT[m*4+2][r] = v.z; qT[m*4+3][r] = v.w;
    }
  }
  if (tid < 64) { qs[tid] = sq[q0+tid]; cnt[tid] = 0; w19[tid] = INFINITY; }
  for (int t = tid; t < 64*KNN; t += 256) { ld[t/KNN][t%KNN] = INFINITY; li[t/KNN][t%KNN] = 0x7fffffff; }

  int qrow0 = (tid >> 4) * 4;
  int crow0 = (tid & 15) * 4;

  for (int tile = 0; tile < TILES_PER_RANGE; tile++) {
    int ct0 = c0 + tile*64;
    {
      int m = tid & 15;
      int rbase = tid >> 4;
      #pragma unroll
      for (int p = 0; p < 4; p++) {
        int r = rbase + p*16;
        float4 v = *(const float4*)(h + (size_t)(ct0+r)*64 + m*4);
        cT[m*4+0][r] = v.x; cT[m*4+1][r] = v.y; cT[m*4+2][r] = v.z; cT[m*4+3][r] = v.w;
      }
    }
    if (tid < 64) cs[tid] = sq[ct0+tid];
    __syncthreads();

    float acc[4][4];
    #pragma unroll
    for (int i=0;i<4;i++)
      #pragma unroll
      for (int j=0;j<4;j++) acc[i][j] = 0.f;

    #pragma unroll 4
    for (int d = 0; d < 64; d++) {
      float4 qv = *(float4*)&qT[d][qrow0];
      float4 cv = *(float4*)&cT[d][crow0];
      acc[0][0] += qv.x*cv.x; acc[0][1] += qv.x*cv.y; acc[0][2] += qv.x*cv.z; acc[0][3] += qv.x*cv.w;
      acc[1][0] += qv.y*cv.x; acc[1][1] += qv.y*cv.y; acc[1][2] += qv.y*cv.z; acc[1][3] += qv.y*cv.w;
      acc[2][0] += qv.z*cv.x; acc[2][1] += qv.z*cv.y; acc[2][2] += qv.z*cv.z; acc[2][3] += qv.z*cv.w;
      acc[3][0] += qv.w*cv.x; acc[3][1] += qv.w*cv.y; acc[3][2] += qv.w*cv.z; acc[3][3] += qv.w*cv.w;
    }

    #pragma unroll
    for (int i=0;i<4;i++) {
      int q = qrow0 + i;
      float qsv = qs[q];
      float w = w19[q];
      #pragma unroll
      for (int j=0;j<4;j++) {
        float d = (qsv + cs[crow0+j]) - 2.0f*acc[i][j];
        if (d < w) {
          int slot = atomicAdd(&cnt[q], 1);
          candd[q*65 + slot] = d;
          candi[q*65 + slot] = ct0 + crow0 + j;
        }
      }
    }
    __syncthreads();

    if (tid < 64) {
      int n = cnt[tid];
      for (int s = 0; s < n; s++)
        lex_insert(ld[tid], li[tid], candd[tid*65+s], candi[tid*65+s]);
      w19[tid] = ld[tid][KNN-1];
      cnt[tid] = 0;
    }
    // next tile's post-staging __syncthreads orders phase2 before filter
  }

  __syncthreads();
  for (int t = tid; t < 64*KNN; t += 256) {
    int q = t / KNN, k = t % KNN;
    size_t o = ((size_t)(q0+q)*NRANGE + rg)*KNN + k;
    pd[o] = ld[q][k];
    pi[o] = li[q][k];
  }
}

// ---------------- knn D=3: packed float4, filtered selection ----------------
__global__ __launch_bounds__(256, 2) void knn3_tiled(const float4* __restrict__ xp,
                                                     float* __restrict__ pd,
                                                     int* __restrict__ pi) {
  __shared__ float4 qb4[64];
  __shared__ float4 cb4[64];
  __shared__ float ld[64][21];
  __shared__ int   li[64][21];
  __shared__ float candd[64*65];
  __shared__ int   candi[64*65];
  __shared__ int   cnt[64];
  __shared__ float w19[64];
  int tid = threadIdx.x;
  int qb = blockIdx.x >> 2;
  int rg = blockIdx.x & 3;
  int q0 = qb*64, c0 = rg*C_RANGE;

  if (tid < 64) { qb4[tid] = xp[q0+tid]; cnt[tid] = 0; w19[tid] = INFINITY; }
  for (int t = tid; t < 64*KNN; t += 256) { ld[t/KNN][t%KNN] = INFINITY; li[t/KNN][t%KNN] = 0x7fffffff; }

  int qrow0 = (tid >> 4) * 4;
  int crow0 = (tid & 15) * 4;

  for (int tile = 0; tile < TILES_PER_RANGE; tile++) {
    int ct0 = c0 + tile*64;
    if (tid < 64) cb4[tid] = xp[ct0+tid];
    __syncthreads();

    float4 qv[4], cv[4];
    #pragma unroll
    for (int i=0;i<4;i++) qv[i] = qb4[qrow0+i];
    #pragma unroll
    for (int j=0;j<4;j++) cv[j] = cb4[crow0+j];
    #pragma unroll
    for (int i=0;i<4;i++) {
      int q = qrow0 + i;
      float w = w19[q];
      #pragma unroll
      for (int j=0;j<4;j++) {
        float d = (qv[i].w + cv[j].w)
                - 2.0f*(qv[i].x*cv[j].x + qv[i].y*cv[j].y + qv[i].z*cv[j].z);
        if (d < w) {
          int slot = atomicAdd(&cnt[q], 1);
          candd[q*65 + slot] = d;
          candi[q*65 + slot] = ct0 + crow0 + j;
        }
      }
    }
    __syncthreads();

    if (tid < 64) {
      int n = cnt[tid];
      for (int s = 0; s < n; s++)
        lex_insert(ld[tid], li[tid], candd[tid*65+s], candi[tid*65+s]);
      w19[tid] = ld[tid][KNN-1];
      cnt[tid] = 0;
    }
  }

  __syncthreads();
  for (int t = tid; t < 64*KNN; t += 256) {
    int q = t / KNN, k = t % KNN;
    size_t o = ((size_t)(q0+q)*NRANGE + rg)*KNN + k;
    pd[o] = ld[q][k];
    pi[o] = li[q][k];
  }
}

// ---------------- merge NRANGE sorted partial lists -> top-20 ----------------
__global__ void knn_merge_kernel(const float* __restrict__ pd, const int* __restrict__ pi,
                                 int* __restrict__ out_idx) {
  int qi = blockIdx.x*256 + threadIdx.x;
  const float* bd = pd + (size_t)qi*NRANGE*KNN;
  const int*   bi = pi + (size_t)qi*NRANGE*KNN;
  int ptr[NRANGE];
  #pragma unroll
  for (int r=0;r<NRANGE;r++) ptr[r] = 0;
  for (int k = 0; k < KNN; k++) {
    float best = INFINITY; int besti = 0x7fffffff; int br = 0;
    #pragma unroll
    for (int r = 0; r < NRANGE; r++) {
      float d = bd[r*KNN + ptr[r]];
      int   ii = bi[r*KNN + ptr[r]];
      bool better = (ptr[r] < KNN) && (d < best || (d == best && ii < besti));
      if (better) { best = d; besti = ii; br = r; }
    }
    #pragma unroll
    for (int r=0;r<NRANGE;r++) ptr[r] += (r == br) ? 1 : 0;
    out_idx[qi*KNN + k] = besti;
  }
}

// ---------------- edge_conv1 precompute ----------------
__global__ void cg1_kernel(const float* __restrict__ x, const float* __restrict__ W1,
                           const float* __restrict__ b1,
                           float* __restrict__ C1, float* __restrict__ G1) {
  int gid = blockIdx.x*256 + threadIdx.x;   // 16384*64
  int i = gid >> 6, c = gid & 63;
  float x0 = x[i*3+0], x1 = x[i*3+1], x2 = x[i*3+2];
  float wt0 = W1[0*64+c], wt1 = W1[1*64+c], wt2 = W1[2*64+c];
  float wb0 = W1[3*64+c], wb1 = W1[4*64+c], wb2 = W1[5*64+c];
  C1[gid] = x0*(wt0-wb0) + x1*(wt1-wb1) + x2*(wt2-wb2) + b1[c];
  G1[gid] = x0*wb0 + x1*wb1 + x2*wb2;
}

// ---------------- gather + max + relu ----------------
template<int C>
__global__ void maxrelu_kernel(const float* __restrict__ Ci, const float* __restrict__ G,
                               const int* __restrict__ idx, float* __restrict__ out) {
  int gid = blockIdx.x*256 + threadIdx.x;
  int i = gid / C, c = gid % C;
  float base = Ci[gid];
  float m = -INFINITY;
  for (int j=0; j<KNN; j++) {
    int jj = idx[i*KNN + j];
    m = fmaxf(m, base + G[(long)jj*C + c]);
  }
  out[gid] = fmaxf(m, 0.0f);
}

// ---------------- W2 diff ----------------
__global__ void wd2_kernel(const float* __restrict__ W2, float* __restrict__ Wd) {
  int gid = blockIdx.x*256 + threadIdx.x;   // 64*128
  int d = gid >> 7, c = gid & 127;
  Wd[gid] = W2[d*128+c] - W2[(d+64)*128+c];
}

// ---------------- edge_conv2 precompute ----------------
__global__ void cg2_kernel(const float* __restrict__ h1, const float* __restrict__ W2,
                           const float* __restrict__ Wd, const float* __restrict__ b2,
                           float* __restrict__ C2, float* __restrict__ G2) {
  int gid = blockIdx.x*256 + threadIdx.x;   // 16384*128
  int i = gid >> 7, c = gid & 127;
  float a = 0.f, g = 0.f;
  for (int d=0; d<64; d++) {
    float hv = h1[i*64 + d];
    a += hv * Wd[d*128 + c];
    g += hv * W2[(d+64)*128 + c];
  }
  C2[gid] = a + b2[c];
  G2[gid] = g;
}

// ---------------- fc1 (relu) ----------------
__global__ void fc1_kernel(const float* __restrict__ h2, const float* __restrict__ w,
                           const float* __restrict__ b, float* __restrict__ out) {
  int gid = blockIdx.x*256 + threadIdx.x;   // 16384*128
  int i = gid >> 7, c = gid & 127;
  float a = 0.f;
  for (int d=0; d<128; d++) a += h2[i*128+d] * w[d*128+c];
  out[gid] = fmaxf(a + b[c], 0.0f);
}

// ---------------- fc2 ----------------
__global__ void fc2_kernel(const float* __restrict__ f1, const float* __restrict__ w,
                           const float* __restrict__ b, float* __restrict__ out) {
  int gid = blockIdx.x*256 + threadIdx.x;   // 16384*40
  int i = gid / 40, c = gid - i*40;
  float a = 0.f;
  for (int d=0; d<128; d++) a += f1[i*128+d] * w[d*40+c];
  out[gid] = a + b[c];
}

extern "C" void kernel_launch(void* const* d_in, const int* in_sizes, int n_in,
                              void* d_out, int out_size, void* d_ws, size_t ws_size,
                              hipStream_t stream) {
  (void)in_sizes; (void)n_in; (void)out_size; (void)ws_size;
  const float* x     = (const float*)d_in[0];
  const float* W1    = (const float*)d_in[1];
  const float* b1    = (const float*)d_in[2];
  const float* W2    = (const float*)d_in[3];
  const float* b2    = (const float*)d_in[4];
  const float* fc1_w = (const float*)d_in[5];
  const float* fc1_b = (const float*)d_in[6];
  const float* fc2_w = (const float*)d_in[7];
  const float* fc2_b = (const float*)d_in[8];
  float* out = (float*)d_out;

  // ---- workspace layout (31.03 MB total, aliased; proven in R2-R4) ----
  char* ws = (char*)d_ws;
  float4* xp4 = (float4*)(ws + 0);          // 262144
  float*  sqh = (float*) (ws + 262144);     // 65536
  int*    idx = (int*)   (ws + 327680);     // 1310720
  float*  Wd2 = (float*) (ws + 1638400);    // 32768
  float*  h1  = (float*) (ws + 1671168);    // 4194304  -> ends 5865472
  float*  h2  = (float*) (ws + 5865472);    // 8388608  -> ends 14254080
  float*  A   = (float*) (ws + 14254080);   // 8388608  -> ends 22642688
  float*  C1  = A;
  float*  G1  = (float*) (ws + 14254080 + 4194304);
  float*  C2  = A;
  float*  f1  = A;
  float*  G2  = (float*) (ws + 22642688);   // 8388608  -> ends 31031296
  float*  pd  = (float*) (ws + 5865472);    // partial dists (5.24 MB used; aliases h2, dead then)
  int*    pi  = (int*)   (ws + 16351232);   // partial idxs  (5.24 MB used; aliases A-tail, dead then)

  pack3_kernel <<<64,   256, 0, stream>>>(x, xp4);
  knn3_tiled   <<<1024, 256, 0, stream>>>(xp4, pd, pi);
  knn_merge_kernel<<<64,256, 0, stream>>>(pd, pi, idx);
  cg1_kernel   <<<4096, 256, 0, stream>>>(x, W1, b1, C1, G1);
  maxrelu_kernel<64> <<<4096, 256, 0, stream>>>(C1, G1, idx, h1);
  sq64_kernel  <<<64,   256, 0, stream>>>(h1, sqh);
  knn64_tiled  <<<1024, 256, 0, stream>>>(h1, sqh, pd, pi);
  knn_merge_kernel<<<64,256, 0, stream>>>(pd, pi, idx);
  wd2_kernel   <<<32,   256, 0, stream>>>(W2, Wd2);
  cg2_kernel   <<<8192, 256, 0, stream>>>(h1, W2, Wd2, b2, C2, G2);
  maxrelu_kernel<128><<<8192, 256, 0, stream>>>(C2, G2, idx, h2);
  fc1_kernel   <<<8192, 256, 0, stream>>>(h2, fc1_w, fc1_b, f1);
  fc2_kernel   <<<2560, 256, 0, stream>>>(f1, fc2_w, fc2_b, out);
}

// Round 6
// 5021.413 us; speedup vs baseline: 3.3764x; 1.0470x over previous
//
#include <hip/hip_runtime.h>
#include <math.h>

#define N_PTS 16384
#define KNN 20
#define NRANGE 4
#define C_RANGE (N_PTS / NRANGE)       // 4096
#define TILES_PER_RANGE (C_RANGE / 64) // 64

// ---------------- pack x + squared norm ----------------
__global__ void pack3_kernel(const float* __restrict__ x, float4* __restrict__ xp) {
  int i = blockIdx.x * blockDim.x + threadIdx.x;
  {
    #pragma clang fp contract(off)
    float a = x[i*3+0], b = x[i*3+1], c = x[i*3+2];
    xp[i] = make_float4(a, b, c, a*a + b*b + c*c);
  }
}

__global__ void sq64_kernel(const float* __restrict__ h, float* __restrict__ sq) {
  int i = blockIdx.x * blockDim.x + threadIdx.x;
  const float4* r = (const float4*)(h + (long)i*64);
  {
    #pragma clang fp contract(off)
    float ax=0.f, ay=0.f, az=0.f, aw=0.f;
    for (int t=0; t<16; t++) {
      float4 v = r[t];
      ax += v.x*v.x; ay += v.y*v.y; az += v.z*v.z; aw += v.w*v.w;
    }
    sq[i] = (ax+ay)+(az+aw);
  }
}

// lex insert of survivor (d, idx) into sorted top-20 (row stride 21)
__device__ __forceinline__ void lex_insert(float* ldq, int* liq, float d, int idx) {
  float d19 = ldq[KNN-1]; int i19 = liq[KNN-1];
  if (d < d19 || (d == d19 && idx < i19)) {
    int p = KNN-1;
    while (p > 0) {
      float pd = ldq[p-1]; int pi = liq[p-1];
      if (pd > d || (pd == d && pi > idx)) { ldq[p] = pd; liq[p] = pi; p--; }
      else break;
    }
    ldq[p] = d; liq[p] = idx;
  }
}

// ---------------- knn D=64: aligned transposed tiles + reg prefetch ----------------
__global__ __launch_bounds__(256, 2) void knn64_tiled(const float* __restrict__ h,
                                                      const float* __restrict__ sq,
                                                      float* __restrict__ pd,
                                                      int* __restrict__ pi) {
  __shared__ float qT[64][68];    // [dim][query], 272B row = 16B-aligned
  __shared__ float cT[64][68];    // [dim][cand]
  __shared__ float qs[64], cs[64];
  __shared__ float ld[64][21];
  __shared__ int   li[64][21];
  __shared__ float candd[64*65];
  __shared__ int   candi[64*65];
  __shared__ int   cnt[64];
  __shared__ float w19[64];
  int tid = threadIdx.x;
  int qb = blockIdx.x >> 2;
  int rg = blockIdx.x & 3;
  int q0 = qb*64, c0 = rg*C_RANGE;

  int m  = tid >> 4;   // col chunk 0..15 (dims m*4..m*4+3)
  int r0 = tid & 15;   // row base

  // stage qT transposed: wave-level 2-way LDS write banks, coalesced global
  #pragma unroll
  for (int p = 0; p < 4; p++) {
    int r = r0 + p*16;
    float4 v = *(const float4*)(h + (size_t)(q0+r)*64 + m*4);
    qT[m*4+0][r] = v.x; qT[m*4+1][r] = v.y; qT[m*4+2][r] = v.z; qT[m*4+3][r] = v.w;
  }
  if (tid < 64) { qs[tid] = sq[q0+tid]; cnt[tid] = 0; w19[tid] = INFINITY; }
  for (int t = tid; t < 64*KNN; t += 256) { ld[t/KNN][t%KNN] = INFINITY; li[t/KNN][t%KNN] = 0x7fffffff; }

  int qrow0 = (tid >> 4) * 4;
  int crow0 = (tid & 15) * 4;

  // prefetch tile 0 candidates into registers
  float4 pv[4]; float psq = 0.f;
  #pragma unroll
  for (int p = 0; p < 4; p++)
    pv[p] = *(const float4*)(h + (size_t)(c0 + r0 + p*16)*64 + m*4);
  if (tid < 64) psq = sq[c0 + tid];

  for (int tile = 0; tile < TILES_PER_RANGE; tile++) {
    int ct0 = c0 + tile*64;
    // write prefetched tile into cT
    #pragma unroll
    for (int p = 0; p < 4; p++) {
      int r = r0 + p*16;
      cT[m*4+0][r] = pv[p].x; cT[m*4+1][r] = pv[p].y; cT[m*4+2][r] = pv[p].z; cT[m*4+3][r] = pv[p].w;
    }
    if (tid < 64) cs[tid] = psq;
    // prefetch next tile (clamped; last-tile value unused)
    {
      int tn = tile+1 < TILES_PER_RANGE ? tile+1 : TILES_PER_RANGE-1;
      int cn0 = c0 + tn*64;
      #pragma unroll
      for (int p = 0; p < 4; p++)
        pv[p] = *(const float4*)(h + (size_t)(cn0 + r0 + p*16)*64 + m*4);
      if (tid < 64) psq = sq[cn0 + tid];
    }
    __syncthreads();   // (B) cT/cs ready

    float acc[4][4];
    #pragma unroll
    for (int i=0;i<4;i++)
      #pragma unroll
      for (int j=0;j<4;j++) acc[i][j] = 0.f;

    #pragma unroll 4
    for (int d = 0; d < 64; d++) {
      float4 qv = *(float4*)&qT[d][qrow0];   // 16B-aligned -> ds_read_b128 (broadcast)
      float4 cv = *(float4*)&cT[d][crow0];   // 16B-aligned -> ds_read_b128 (2-way)
      acc[0][0] += qv.x*cv.x; acc[0][1] += qv.x*cv.y; acc[0][2] += qv.x*cv.z; acc[0][3] += qv.x*cv.w;
      acc[1][0] += qv.y*cv.x; acc[1][1] += qv.y*cv.y; acc[1][2] += qv.y*cv.z; acc[1][3] += qv.y*cv.w;
      acc[2][0] += qv.z*cv.x; acc[2][1] += qv.z*cv.y; acc[2][2] += qv.z*cv.z; acc[2][3] += qv.z*cv.w;
      acc[3][0] += qv.w*cv.x; acc[3][1] += qv.w*cv.y; acc[3][2] += qv.w*cv.z; acc[3][3] += qv.w*cv.w;
    }

    #pragma unroll
    for (int i=0;i<4;i++) {
      int q = qrow0 + i;
      float qsv = qs[q];
      float w = w19[q];
      #pragma unroll
      for (int j=0;j<4;j++) {
        float d = (qsv + cs[crow0+j]) - 2.0f*acc[i][j];
        if (d < w) {
          int slot = atomicAdd(&cnt[q], 1);
          candd[q*65 + slot] = d;
          candi[q*65 + slot] = ct0 + crow0 + j;
        }
      }
    }
    __syncthreads();   // (C) pushes complete

    if (tid < 64) {
      int n = cnt[tid];
      for (int s = 0; s < n; s++)
        lex_insert(ld[tid], li[tid], candd[tid*65+s], candi[tid*65+s]);
      w19[tid] = ld[tid][KNN-1];
      cnt[tid] = 0;
    }
    // loop-head cT writes by waves 1-3 are safe: (C) ensured compute done;
    // wave0 writes only after its insert; (B) of t+1 waits for wave0.
  }

  __syncthreads();
  for (int t = tid; t < 64*KNN; t += 256) {
    int q = t / KNN, k = t % KNN;
    size_t o = ((size_t)(q0+q)*NRANGE + rg)*KNN + k;
    pd[o] = ld[q][k];
    pi[o] = li[q][k];
  }
}

// ---------------- knn D=3: packed float4 + reg prefetch ----------------
__global__ __launch_bounds__(256, 2) void knn3_tiled(const float4* __restrict__ xp,
                                                     float* __restrict__ pd,
                                                     int* __restrict__ pi) {
  __shared__ float4 qb4[64];
  __shared__ float4 cb4[64];
  __shared__ float ld[64][21];
  __shared__ int   li[64][21];
  __shared__ float candd[64*65];
  __shared__ int   candi[64*65];
  __shared__ int   cnt[64];
  __shared__ float w19[64];
  int tid = threadIdx.x;
  int qb = blockIdx.x >> 2;
  int rg = blockIdx.x & 3;
  int q0 = qb*64, c0 = rg*C_RANGE;

  if (tid < 64) { qb4[tid] = xp[q0+tid]; cnt[tid] = 0; w19[tid] = INFINITY; }
  for (int t = tid; t < 64*KNN; t += 256) { ld[t/KNN][t%KNN] = INFINITY; li[t/KNN][t%KNN] = 0x7fffffff; }

  int qrow0 = (tid >> 4) * 4;
  int crow0 = (tid & 15) * 4;

  float4 pv; 
  if (tid < 64) pv = xp[c0 + tid];

  for (int tile = 0; tile < TILES_PER_RANGE; tile++) {
    int ct0 = c0 + tile*64;
    if (tid < 64) cb4[tid] = pv;
    {
      int tn = tile+1 < TILES_PER_RANGE ? tile+1 : TILES_PER_RANGE-1;
      if (tid < 64) pv = xp[c0 + tn*64 + tid];
    }
    __syncthreads();

    float4 qv[4], cv[4];
    #pragma unroll
    for (int i=0;i<4;i++) qv[i] = qb4[qrow0+i];
    #pragma unroll
    for (int j=0;j<4;j++) cv[j] = cb4[crow0+j];
    #pragma unroll
    for (int i=0;i<4;i++) {
      int q = qrow0 + i;
      float w = w19[q];
      #pragma unroll
      for (int j=0;j<4;j++) {
        float d = (qv[i].w + cv[j].w)
                - 2.0f*(qv[i].x*cv[j].x + qv[i].y*cv[j].y + qv[i].z*cv[j].z);
        if (d < w) {
          int slot = atomicAdd(&cnt[q], 1);
          candd[q*65 + slot] = d;
          candi[q*65 + slot] = ct0 + crow0 + j;
        }
      }
    }
    __syncthreads();

    if (tid < 64) {
      int n = cnt[tid];
      for (int s = 0; s < n; s++)
        lex_insert(ld[tid], li[tid], candd[tid*65+s], candi[tid*65+s]);
      w19[tid] = ld[tid][KNN-1];
      cnt[tid] = 0;
    }
  }

  __syncthreads();
  for (int t = tid; t < 64*KNN; t += 256) {
    int q = t / KNN, k = t % KNN;
    size_t o = ((size_t)(q0+q)*NRANGE + rg)*KNN + k;
    pd[o] = ld[q][k];
    pi[o] = li[q][k];
  }
}

// ---------------- merge NRANGE sorted partial lists -> top-20 ----------------
__global__ void knn_merge_kernel(const float* __restrict__ pd, const int* __restrict__ pi,
                                 int* __restrict__ out_idx) {
  int qi = blockIdx.x*256 + threadIdx.x;
  const float* bd = pd + (size_t)qi*NRANGE*KNN;
  const int*   bi = pi + (size_t)qi*NRANGE*KNN;
  int ptr[NRANGE];
  #pragma unroll
  for (int r=0;r<NRANGE;r++) ptr[r] = 0;
  for (int k = 0; k < KNN; k++) {
    float best = INFINITY; int besti = 0x7fffffff; int br = 0;
    #pragma unroll
    for (int r = 0; r < NRANGE; r++) {
      float d = bd[r*KNN + ptr[r]];
      int   ii = bi[r*KNN + ptr[r]];
      bool better = (ptr[r] < KNN) && (d < best || (d == best && ii < besti));
      if (better) { best = d; besti = ii; br = r; }
    }
    #pragma unroll
    for (int r=0;r<NRANGE;r++) ptr[r] += (r == br) ? 1 : 0;
    out_idx[qi*KNN + k] = besti;
  }
}

// ---------------- edge_conv1 precompute ----------------
__global__ void cg1_kernel(const float* __restrict__ x, const float* __restrict__ W1,
                           const float* __restrict__ b1,
                           float* __restrict__ C1, float* __restrict__ G1) {
  int gid = blockIdx.x*256 + threadIdx.x;   // 16384*64
  int i = gid >> 6, c = gid & 63;
  float x0 = x[i*3+0], x1 = x[i*3+1], x2 = x[i*3+2];
  float wt0 = W1[0*64+c], wt1 = W1[1*64+c], wt2 = W1[2*64+c];
  float wb0 = W1[3*64+c], wb1 = W1[4*64+c], wb2 = W1[5*64+c];
  C1[gid] = x0*(wt0-wb0) + x1*(wt1-wb1) + x2*(wt2-wb2) + b1[c];
  G1[gid] = x0*wb0 + x1*wb1 + x2*wb2;
}

// ---------------- gather + max + relu ----------------
template<int C>
__global__ void maxrelu_kernel(const float* __restrict__ Ci, const float* __restrict__ G,
                               const int* __restrict__ idx, float* __restrict__ out) {
  int gid = blockIdx.x*256 + threadIdx.x;
  int i = gid / C, c = gid % C;
  float base = Ci[gid];
  float m = -INFINITY;
  for (int j=0; j<KNN; j++) {
    int jj = idx[i*KNN + j];
    m = fmaxf(m, base + G[(long)jj*C + c]);
  }
  out[gid] = fmaxf(m, 0.0f);
}

// ---------------- W2 diff ----------------
__global__ void wd2_kernel(const float* __restrict__ W2, float* __restrict__ Wd) {
  int gid = blockIdx.x*256 + threadIdx.x;   // 64*128
  int d = gid >> 7, c = gid & 127;
  Wd[gid] = W2[d*128+c] - W2[(d+64)*128+c];
}

// ---------------- edge_conv2 precompute ----------------
__global__ void cg2_kernel(const float* __restrict__ h1, const float* __restrict__ W2,
                           const float* __restrict__ Wd, const float* __restrict__ b2,
                           float* __restrict__ C2, float* __restrict__ G2) {
  int gid = blockIdx.x*256 + threadIdx.x;   // 16384*128
  int i = gid >> 7, c = gid & 127;
  float a = 0.f, g = 0.f;
  for (int d=0; d<64; d++) {
    float hv = h1[i*64 + d];
    a += hv * Wd[d*128 + c];
    g += hv * W2[(d+64)*128 + c];
  }
  C2[gid] = a + b2[c];
  G2[gid] = g;
}

// ---------------- fc1 (relu) ----------------
__global__ void fc1_kernel(const float* __restrict__ h2, const float* __restrict__ w,
                           const float* __restrict__ b, float* __restrict__ out) {
  int gid = blockIdx.x*256 + threadIdx.x;   // 16384*128
  int i = gid >> 7, c = gid & 127;
  float a = 0.f;
  for (int d=0; d<128; d++) a += h2[i*128+d] * w[d*128+c];
  out[gid] = fmaxf(a + b[c], 0.0f);
}

// ---------------- fc2 ----------------
__global__ void fc2_kernel(const float* __restrict__ f1, const float* __restrict__ w,
                           const float* __restrict__ b, float* __restrict__ out) {
  int gid = blockIdx.x*256 + threadIdx.x;   // 16384*40
  int i = gid / 40, c = gid - i*40;
  float a = 0.f;
  for (int d=0; d<128; d++) a += f1[i*128+d] * w[d*40+c];
  out[gid] = a + b[c];
}

extern "C" void kernel_launch(void* const* d_in, const int* in_sizes, int n_in,
                              void* d_out, int out_size, void* d_ws, size_t ws_size,
                              hipStream_t stream) {
  (void)in_sizes; (void)n_in; (void)out_size; (void)ws_size;
  const float* x     = (const float*)d_in[0];
  const float* W1    = (const float*)d_in[1];
  const float* b1    = (const float*)d_in[2];
  const float* W2    = (const float*)d_in[3];
  const float* b2    = (const float*)d_in[4];
  const float* fc1_w = (const float*)d_in[5];
  const float* fc1_b = (const float*)d_in[6];
  const float* fc2_w = (const float*)d_in[7];
  const float* fc2_b = (const float*)d_in[8];
  float* out = (float*)d_out;

  // ---- workspace layout (31.03 MB total, aliased; proven R2-R5) ----
  char* ws = (char*)d_ws;
  float4* xp4 = (float4*)(ws + 0);          // 262144
  float*  sqh = (float*) (ws + 262144);     // 65536
  int*    idx = (int*)   (ws + 327680);     // 1310720
  float*  Wd2 = (float*) (ws + 1638400);    // 32768
  float*  h1  = (float*) (ws + 1671168);    // 4194304  -> ends 5865472
  float*  h2  = (float*) (ws + 5865472);    // 8388608  -> ends 14254080
  float*  A   = (float*) (ws + 14254080);   // 8388608  -> ends 22642688
  float*  C1  = A;
  float*  G1  = (float*) (ws + 14254080 + 4194304);
  float*  C2  = A;
  float*  f1  = A;
  float*  G2  = (float*) (ws + 22642688);   // 8388608  -> ends 31031296
  float*  pd  = (float*) (ws + 5865472);    // partial dists (aliases h2, dead then)
  int*    pi  = (int*)   (ws + 16351232);   // partial idxs  (aliases A-tail, dead then)

  pack3_kernel <<<64,   256, 0, stream>>>(x, xp4);
  knn3_tiled   <<<1024, 256, 0, stream>>>(xp4, pd, pi);
  knn_merge_kernel<<<64,256, 0, stream>>>(pd, pi, idx);
  cg1_kernel   <<<4096, 256, 0, stream>>>(x, W1, b1, C1, G1);
  maxrelu_kernel<64> <<<4096, 256, 0, stream>>>(C1, G1, idx, h1);
  sq64_kernel  <<<64,   256, 0, stream>>>(h1, sqh);
  knn64_tiled  <<<1024, 256, 0, stream>>>(h1, sqh, pd, pi);
  knn_merge_kernel<<<64,256, 0, stream>>>(pd, pi, idx);
  wd2_kernel   <<<32,   256, 0, stream>>>(W2, Wd2);
  cg2_kernel   <<<8192, 256, 0, stream>>>(h1, W2, Wd2, b2, C2, G2);
  maxrelu_kernel<128><<<8192, 256, 0, stream>>>(C2, G2, idx, h2);
  fc1_kernel   <<<8192, 256, 0, stream>>>(h2, fc1_w, fc1_b, f1);
  fc2_kernel   <<<2560, 256, 0, stream>>>(f1, fc2_w, fc2_b, out);
}